// Round 9
// baseline (3134.728 us; speedup 1.0000x reference)
//
#include <hip/hip_runtime.h>
#include <math.h>

// Problem constants
#define B_    256
#define NPTS  1024
#define T_    50

// ---------------------------------------------------------------------------
// ws layout (bytes):
//   [0,       786432)   wp   f32 [64][3][256][4]  packed W_hh (round-7 layout)
//   [786432,  1310720)  henc u32 [256][512]       (f32-bit maxpool via atomicMax)
// ---------------------------------------------------------------------------

__global__ __launch_bounds__(256) void prep_kernel(
    const float* __restrict__ whh, float* __restrict__ wp,
    unsigned* __restrict__ henc) {
  int idx = blockIdx.x * 256 + threadIdx.x;   // grid 768*256 = 196608
  if (idx < 196608) {
    int c = idx & 3;
    int r = idx >> 2;            // (k4*3+j)*256 + t
    int t2 = r & 255;
    int q = r >> 8;              // k4*3 + j
    int j = q % 3;
    int k4 = q / 3;
    wp[idx] = whh[(j * 256 + t2) * 256 + (k4 * 4 + c)];
  }
  if (idx < 131072) henc[idx] = 0u;           // bits 0 == +0.0f; relu>=0 valid
}

// ---------------------------------------------------------------------------
// Encoder (byte-identical math to passing rounds; round-4 exact).
// ---------------------------------------------------------------------------
__global__ __launch_bounds__(1024) void enc_kernel(
    const float* __restrict__ data,
    const float* __restrict__ w1, const float* __restrict__ b1,
    const float* __restrict__ w2, const float* __restrict__ b2,
    const float* __restrict__ w3, const float* __restrict__ b3,
    unsigned* __restrict__ henc) {
  __shared__ float h2t[128][66];
  const int t = threadIdx.x;
  const int b = blockIdx.x >> 1;
  const int half = blockIdx.x & 1;
  const int lane = t & 63;
  const int wv = __builtin_amdgcn_readfirstlane(t >> 6);   // wave id 0..15

  float m[32];
#pragma unroll
  for (int o = 0; o < 32; ++o) m[o] = 0.0f;                // relu via max w/ 0
  const float* __restrict__ w3b = w3 + wv * 32;

#pragma unroll 1
  for (int tile = 0; tile < 8; ++tile) {
    {
      const int ptg = b * NPTS + half * 512 + tile * 64 + lane;
      const float x0 = data[ptg * 3], x1 = data[ptg * 3 + 1], x2 = data[ptg * 3 + 2];
      float a[8];
#pragma unroll
      for (int c = 0; c < 8; ++c) a[c] = b2[wv * 8 + c];   // s_load
#pragma unroll 4
      for (int j = 0; j < 64; ++j) {                       // w1/b1 uniform
        float hj = fmaf(x0, w1[j], fmaf(x1, w1[64 + j], fmaf(x2, w1[128 + j], b1[j])));
        hj = fmaxf(hj, 0.0f);
        const float* __restrict__ w2r = w2 + j * 128 + wv * 8;  // s_load x8
#pragma unroll
        for (int c = 0; c < 8; ++c) a[c] = fmaf(hj, w2r[c], a[c]);
      }
#pragma unroll
      for (int c = 0; c < 8; ++c) h2t[wv * 8 + c][lane] = fmaxf(a[c], 0.0f);
    }
    __syncthreads();

    float acc[32];
#pragma unroll
    for (int o = 0; o < 32; ++o) acc[o] = b3[wv * 32 + o]; // s_load
#pragma unroll 4
    for (int k = 0; k < 128; ++k) {
      const float hk = h2t[k][lane];                       // ds_read_b32
      const float* __restrict__ wr = w3b + k * 512;        // uniform -> s_load
#pragma unroll
      for (int o = 0; o < 32; ++o) acc[o] = fmaf(hk, wr[o], acc[o]);
    }
#pragma unroll
    for (int o = 0; o < 32; ++o) m[o] = fmaxf(m[o], acc[o]);
    __syncthreads();                                       // h2t reuse guard
  }

#pragma unroll
  for (int off = 32; off > 0; off >>= 1) {
#pragma unroll
    for (int o = 0; o < 32; ++o) m[o] = fmaxf(m[o], __shfl_xor(m[o], off, 64));
  }
  if (lane == 0) {
    unsigned* __restrict__ hr = henc + b * 512 + wv * 32;
#pragma unroll
    for (int o = 0; o < 32; ++o) atomicMax(hr + o, __float_as_uint(m[o]));
  }
}

// ---------------------------------------------------------------------------
// Fast f64 exp (Cody-Waite + degree-13 Taylor, exact 1/k! coeffs, branch-
// free, ~1 ulp for |x| < 700). Perturbs vs libm at ~1e-16 rel -> invisible
// at f32 output rounding (f64-perturbation invariance proven rounds 4-7).
// ---------------------------------------------------------------------------
__device__ __forceinline__ double fexp(double x) {
  const double n = rint(x * 1.44269504088896338700e+00);
  const double r = fma(-n, 1.90821492927058770002e-10,
                       fma(-n, 6.93147180369123816490e-01, x));
  double p = 1.0 / 6227020800.0;                 // 1/13!
  p = fma(p, r, 1.0 / 479001600.0);
  p = fma(p, r, 1.0 / 39916800.0);
  p = fma(p, r, 1.0 / 3628800.0);
  p = fma(p, r, 1.0 / 362880.0);
  p = fma(p, r, 1.0 / 40320.0);
  p = fma(p, r, 1.0 / 5040.0);
  p = fma(p, r, 1.0 / 720.0);
  p = fma(p, r, 1.0 / 120.0);
  p = fma(p, r, 1.0 / 24.0);
  p = fma(p, r, 1.0 / 6.0);
  p = fma(p, r, 0.5);
  p = fma(p, r, 1.0);
  p = fma(p, r, 1.0);
  return ldexp(p, (int)n);
}
__device__ __forceinline__ double fsigm(double x) { return 1.0 / (1.0 + fexp(-x)); }
__device__ __forceinline__ double ftanh(double y) {
  const double e = fexp(-2.0 * y);
  return (1.0 - e) / (1.0 + e);
}

// ---------------------------------------------------------------------------
// GRU rollout, f64. Round-17 = round-11/R4 winner (grid 256, block 576,
// 2 barriers/step, gates t<256, wave-8 out_mlp) with ONE structural delta:
// the matvec is a chunked REGISTER-PREFETCH pipeline exploiting that W_hh
// loads are h-INDEPENDENT (can issue across barriers/gates):
//   * 8 chunks x 4 k4; two named 12-float4 buffers A/B (static names only;
//     runtime-indexed arrays would hit scratch -- R2/R3 lesson).
//   * schedule: consume A(c0), issue A(c2); consume B(c1), issue B(c3); ...
//     tail issues NEXT STEP's c0/c1 -> they cross [B]+gates+[A] (~1500cy
//     cover; the __syncthreads vmcnt-drain at [B] completes them).
//   * compiler emits counted vmcnt waits for register loads automatically;
//     no hand asm, no raw barriers.
//   * consume order = k4 ascending -> FMA sequence BIT-IDENTICAL to R4.
// Rationale: R5/R7/R8 proved the wp stream rate (~25-30 B/cy/CU) invariant
// to wave count / unroll / L1 policy / XCD demand -> the cap is the serial
// wait->compute chain per wave (lockstep latency-bound). Prefetch breaks
// the chain; floor = 786KB @ 64B/cy L1-return ~ 5.1us/step.
// ---------------------------------------------------------------------------
__global__ __launch_bounds__(576) void gru_kernel(
    const float* __restrict__ henc,     // [256][512] (maxpool bits)
    const float* __restrict__ mw1, const float* __restrict__ mb1,
    const float* __restrict__ mw2, const float* __restrict__ mb2,
    const float* __restrict__ mw3, const float* __restrict__ mb3,
    const float* __restrict__ wih, const float* __restrict__ wp,
    const float* __restrict__ bih, const float* __restrict__ bhh,
    const float* __restrict__ ow1, const float* __restrict__ ob1,
    const float* __restrict__ ow2, const float* __restrict__ ob2,
    const float* __restrict__ ow3, const float* __restrict__ ob3,
    float* __restrict__ dout) {
  __shared__ __align__(16) double h_l[256];     // single sample
  __shared__ double pp[3][256];                 // half1 partials [gate][c]
  __shared__ __align__(16) float ow1f[16384];   // phase-0 alias: g1(256d)+g2(128d)
  __shared__ __align__(16) float ow2f[4096];
  __shared__ float ow3f[384];
  __shared__ float wihf[4608];
  __shared__ float bihf[768];
  __shared__ double o1_l[64];
  __shared__ double o2_l[64];
  __shared__ double gia_l[6];

  const int t = threadIdx.x;
  const int s = blockIdx.x;                     // sample

  for (int i = t; i < 4608; i += 576) wihf[i] = wih[i];
  for (int i = t; i < 768; i += 576) bihf[i] = bih[i];

  double* const g1_l = (double*)ow1f;           // 256 doubles (phase 0 only)
  double* const g2_l = (double*)ow1f + 256;     // 128 doubles (phase 0 only)

  // ---- phase 0: gru_h init MLP (512->256->128->256), f64 (round-7 math) --
  if (t < 256) {
    const float* __restrict__ hrow = henc + (s << 9);
    double a = (double)mb1[t];
#pragma unroll 4
    for (int k = 0; k < 512; ++k)
      a = fma((double)hrow[k], (double)mw1[k * 256 + t], a);
    g1_l[t] = fmax(a, 0.0);
  }
  __syncthreads();
  if (t < 128) {
    double a = (double)mb2[t];
#pragma unroll 4
    for (int k = 0; k < 256; ++k) a = fma(g1_l[k], (double)mw2[k * 128 + t], a);
    g2_l[t] = fmax(a, 0.0);
  }
  __syncthreads();
  if (t < 256) {
    double a = (double)mb3[t];
#pragma unroll 4
    for (int k = 0; k < 128; ++k) a = fma(g2_l[k], (double)mw3[k * 256 + t], a);
    h_l[t] = a;
  }
  if (t < 6) gia_l[t] = 0.0;
  __syncthreads();                    // phase-0 reads of g1/g2 complete

  // ---- stage out_mlp f32 weights into LDS (overwrites g1/g2 region) ----
  for (int i = t; i < 16384; i += 576) ow1f[i] = ow1[i];
  for (int i = t; i < 4096; i += 576) ow2f[i] = ow2[i];
  if (t < 384) ow3f[t] = ow3[t];
  // (visible to wave 8 after the post-prologue __syncthreads)

  // ---- thread constants ----
  const int c = t & 255;
  const int hh = (t >> 8) & 1;                 // k-half (t<512)
  const int khome = hh << 5;                   // k4 range [khome, khome+32)
  const double br = (t < 512 && hh == 0) ? (double)bhh[c] : 0.0;
  const double bz = (t < 512 && hh == 0) ? (double)bhh[256 + c] : 0.0;
  const double bn = (t < 512 && hh == 0) ? (double)bhh[512 + c] : 0.0;
  double hreg = (t < 256) ? h_l[c] : 0.0;      // own phase-0 write
  const float* const wpc = wp + c * 4;

  // out_mlp constants (wave 8)
  const int ln = t & 63;
  double ob1d = 0.0, ob2d = 0.0, ob3d = 0.0;
  if (t >= 512) {
    ob1d = (double)ob1[ln];
    ob2d = (double)ob2[ln];
    if (ln < 6) ob3d = (double)ob3[ln];
  }

  double ar, az, an;

  // prefetch buffers: 2 chunks x 4 k4 x 3 float4 -- STATIC NAMES ONLY
  float4 A0, A1, A2, A3, A4, A5, A6, A7, A8, A9, A10, A11;
  float4 B0, B1, B2, B3, B4, B5, B6, B7, B8, B9, B10, B11;

  // FMA order per k4 identical to round-4's chain (bit-identical output):
  // ar: w.x,w.y,w.z,w.w then az x4 then an x4, k4 ascending.
#define MV_CORE(k4, WR, WZ, WN) {                                            \
    const double2 ha = *(const double2*)(h_l + ((k4) << 2));                 \
    const double2 hb = *(const double2*)(h_l + ((k4) << 2) + 2);             \
    ar = fma(ha.x, (double)WR.x, ar); ar = fma(ha.y, (double)WR.y, ar);      \
    ar = fma(hb.x, (double)WR.z, ar); ar = fma(hb.y, (double)WR.w, ar);      \
    az = fma(ha.x, (double)WZ.x, az); az = fma(ha.y, (double)WZ.y, az);      \
    az = fma(hb.x, (double)WZ.z, az); az = fma(hb.y, (double)WZ.w, az);      \
    an = fma(ha.x, (double)WN.x, an); an = fma(ha.y, (double)WN.y, an);      \
    an = fma(hb.x, (double)WN.z, an); an = fma(hb.y, (double)WN.w, an);      \
  }
#define LD3(WR, WZ, WN, k4) {                                                \
    const float* p_ = wpc + (k4) * 3072;                                     \
    WR = *(const float4*)(p_);                                               \
    WZ = *(const float4*)(p_ + 1024);                                        \
    WN = *(const float4*)(p_ + 2048);                                        \
  }
#define ISSUE_A(k4b) { LD3(A0,A1,A2,(k4b)) LD3(A3,A4,A5,(k4b)+1)             \
                       LD3(A6,A7,A8,(k4b)+2) LD3(A9,A10,A11,(k4b)+3) }
#define ISSUE_B(k4b) { LD3(B0,B1,B2,(k4b)) LD3(B3,B4,B5,(k4b)+1)             \
                       LD3(B6,B7,B8,(k4b)+2) LD3(B9,B10,B11,(k4b)+3) }
#define CONS_A(k4b)  { MV_CORE((k4b),A0,A1,A2) MV_CORE((k4b)+1,A3,A4,A5)     \
                       MV_CORE((k4b)+2,A6,A7,A8) MV_CORE((k4b)+3,A9,A10,A11) }
#define CONS_B(k4b)  { MV_CORE((k4b),B0,B1,B2) MV_CORE((k4b)+1,B3,B4,B5)     \
                       MV_CORE((k4b)+2,B6,B7,B8) MV_CORE((k4b)+3,B9,B10,B11) }

// one full pipelined 32-k4 pass; tail re-issues chunks 0,1 for the NEXT pass
#define MV_PIPE() {                                                          \
    CONS_A(khome)      ISSUE_A(khome + 8)                                    \
    CONS_B(khome + 4)  ISSUE_B(khome + 12)                                   \
    CONS_A(khome + 8)  ISSUE_A(khome + 16)                                   \
    CONS_B(khome + 12) ISSUE_B(khome + 20)                                   \
    CONS_A(khome + 16) ISSUE_A(khome + 24)                                   \
    CONS_B(khome + 20) ISSUE_B(khome + 28)                                   \
    CONS_A(khome + 24) ISSUE_A(khome)                                        \
    CONS_B(khome + 28) ISSUE_B(khome + 4)                                    \
  }
#define MV_PUBLISH() {                                                       \
    if (hh) { pp[0][c] = ar; pp[1][c] = az; pp[2][c] = an; }                 \
  }

  // ---- prologue: both halves' partials of comb(h0), pipelined the same
  // way (consume order k4-ascending == round-4's JIT pass); its tail
  // pre-issues step-0's chunks 0,1.
  if (t < 512) {
    ar = br; az = bz; an = bn;
    ISSUE_A(khome)
    ISSUE_B(khome + 4)
    MV_PIPE()
    MV_PUBLISH()
  }
  __syncthreads();                    // pp + staged LDS weights visible
                                      // (drains vmcnt: c0/c1 complete)

#pragma unroll 1
  for (int step = 0; step < T_; ++step) {
    // ---- gates (t<256): comb = own half0 (biased) + half1 from pp ----
    if (t < 256) {
      const double cr = ar + pp[0][c];
      const double cz = az + pp[1][c];
      const double cn = an + pp[2][c];
      double gr = (double)bihf[c], gz = (double)bihf[256 + c],
             gn = (double)bihf[512 + c];
#pragma unroll
      for (int a = 0; a < 6; ++a) {
        const double xa = gia_l[a];
        gr = fma((double)wihf[c * 6 + a], xa, gr);
        gz = fma((double)wihf[(256 + c) * 6 + a], xa, gz);
        gn = fma((double)wihf[(512 + c) * 6 + a], xa, gn);
      }
      const double rv = fsigm(cr + gr);
      const double zv = fsigm(cz + gz);
      const double nv = ftanh(fma(rv, cn, gn));
      hreg = fma(zv, hreg - nv, nv);
      h_l[c] = hreg;
    }
    if (t < 512) { ar = br; az = bz; an = bn; }
    __syncthreads();                  // [A] h published

    if (t < 512) {
      // ---- matvec: pipelined pass (chunks 0,1 already in registers) ----
      MV_PIPE()
      MV_PUBLISH()
    } else {
      // ---- out_mlp, wave-private (wave 8) ----
      double a0 = ob1d, a1 = 0.0;     // (ob1 + asc lo) + (asc hi): proven assoc
#pragma unroll 4
      for (int k = 0; k < 128; ++k) {
        a0 = fma(h_l[k], (double)ow1f[k * 64 + ln], a0);
        a1 = fma(h_l[128 + k], (double)ow1f[(128 + k) * 64 + ln], a1);
      }
      o1_l[ln] = fmax(a0 + a1, 0.0);
      __builtin_amdgcn_wave_barrier();                    // own-wave LDS only
      double b0 = ob2d;
#pragma unroll 4
      for (int k = 0; k < 64; ++k)
        b0 = fma(o1_l[k], (double)ow2f[k * 64 + ln], b0);
      o2_l[ln] = fmax(b0, 0.0);
      __builtin_amdgcn_wave_barrier();
      if (ln < 6) {
        double a = ob3d;
#pragma unroll 4
        for (int k = 0; k < 64; ++k)
          a = fma(o2_l[k], (double)ow3f[k * 6 + ln], a);
        const double gi_new = gia_l[ln] + a;
        gia_l[ln] = gi_new;
        dout[s * 300 + step * 6 + ln] = (float)a;              // dws
        dout[76800 + s * 300 + step * 6 + ln] = (float)gi_new; // ws
      }
    }
    __syncthreads();                  // [B] pp + gia ready; drains next c0/c1
  }
#undef MV_CORE
#undef LD3
#undef ISSUE_A
#undef ISSUE_B
#undef CONS_A
#undef CONS_B
#undef MV_PIPE
#undef MV_PUBLISH
}

extern "C" void kernel_launch(void* const* d_in, const int* in_sizes, int n_in,
                              void* d_out, int out_size, void* d_ws, size_t ws_size,
                              hipStream_t stream) {
  const float* data = (const float*)d_in[0];
  // d_in[1] = horizon (always 50)
  const float* ew1 = (const float*)d_in[2];
  const float* eb1 = (const float*)d_in[3];
  const float* ew2 = (const float*)d_in[4];
  const float* eb2 = (const float*)d_in[5];
  const float* ew3 = (const float*)d_in[6];
  const float* eb3 = (const float*)d_in[7];
  const float* mw1 = (const float*)d_in[8];
  const float* mb1 = (const float*)d_in[9];
  const float* mw2 = (const float*)d_in[10];
  const float* mb2 = (const float*)d_in[11];
  const float* mw3 = (const float*)d_in[12];
  const float* mb3 = (const float*)d_in[13];
  const float* wih = (const float*)d_in[14];
  const float* whh = (const float*)d_in[15];
  const float* bih = (const float*)d_in[16];
  const float* bhh = (const float*)d_in[17];
  const float* ow1 = (const float*)d_in[18];
  const float* ob1 = (const float*)d_in[19];
  const float* ow2 = (const float*)d_in[20];
  const float* ob2 = (const float*)d_in[21];
  const float* ow3 = (const float*)d_in[22];
  const float* ob3 = (const float*)d_in[23];
  float* out = (float*)d_out;

  char* ws = (char*)d_ws;
  float*    wp   = (float*)(ws);                 // 786432 B
  unsigned* henc = (unsigned*)(ws + 786432);     // 524288 B -> end 1310720

  prep_kernel<<<768, 256, 0, stream>>>(whh, wp, henc);
  enc_kernel<<<512, 1024, 0, stream>>>(data, ew1, eb1, ew2, eb2, ew3, eb3, henc);
  gru_kernel<<<256, 576, 0, stream>>>((const float*)henc,
                                      mw1, mb1, mw2, mb2, mw3, mb3,
                                      wih, wp, bih, bhh,
                                      ow1, ob1, ow2, ob2, ow3, ob3,
                                      out);
}

// Round 10
// 2832.662 us; speedup vs baseline: 1.1066x; 1.1066x over previous
//
#include <hip/hip_runtime.h>
#include <math.h>

// Problem constants
#define B_    256
#define NPTS  1024
#define T_    50

// ---------------------------------------------------------------------------
// ws layout (bytes):
//   [0,       786432)   wp   f32 [64][3][256][4]  packed W_hh (round-7 layout)
//   [786432,  1310720)  henc u32 [256][512]       (f32-bit maxpool via atomicMax)
//   [1310720, 1310724)  zw   u32 runtime zero (defeats uniformity analysis)
// ---------------------------------------------------------------------------

__global__ __launch_bounds__(256) void prep_kernel(
    const float* __restrict__ whh, float* __restrict__ wp,
    unsigned* __restrict__ henc, unsigned* __restrict__ zw) {
  int idx = blockIdx.x * 256 + threadIdx.x;   // grid 768*256 = 196608
  if (idx < 196608) {
    int c = idx & 3;
    int r = idx >> 2;            // (k4*3+j)*256 + t
    int t2 = r & 255;
    int q = r >> 8;              // k4*3 + j
    int j = q % 3;
    int k4 = q / 3;
    wp[idx] = whh[(j * 256 + t2) * 256 + (k4 * 4 + c)];
  }
  if (idx < 131072) henc[idx] = 0u;           // bits 0 == +0.0f; relu>=0 valid
  if (idx == 0) zw[0] = 0u;                   // runtime zero for enc
}

// ---------------------------------------------------------------------------
// Encoder. Round-18 delta vs the passing round-4 version: weight loads in
// the two hot loops moved from the SCALAR path (s_load) to the VECTOR path
// (global_load_dwordx4) via a runtime-zero lane-varying offset (lz).
// WHY: SMEM and DS share lgkmcnt, and SMEM returns out-of-order -> the
// compiler must emit lgkmcnt(0) before using the ds_read (hk), exposing the
// full sK$-miss latency (~200cy; w3 slice is 256KB/tile/CU vs 16KB sK$)
// EVERY k iteration. Measured VALUBusy ~36% matches 66cy FMA + ~130cy stall.
// Vector loads wait on vmcnt (separate counter) and pipeline deeply; the
// ds_read then uses a counted DS-only lgkmcnt. Same addresses, same values,
// same FMA order -> bit-identical output.
// ---------------------------------------------------------------------------
__global__ __launch_bounds__(1024) void enc_kernel(
    const float* __restrict__ data,
    const float* __restrict__ w1, const float* __restrict__ b1,
    const float* __restrict__ w2, const float* __restrict__ b2,
    const float* __restrict__ w3, const float* __restrict__ b3,
    unsigned* __restrict__ henc, const unsigned* __restrict__ zw) {
  __shared__ float h2t[128][66];
  const int t = threadIdx.x;
  const int b = blockIdx.x >> 1;
  const int half = blockIdx.x & 1;
  const int lane = t & 63;
  const int wv = __builtin_amdgcn_readfirstlane(t >> 6);   // wave id 0..15

  // runtime zero x lane-varying -> compiler cannot prove uniform or zero;
  // forces vector-path loads for every pointer offset by lz. lz == 0.
  const int lz = (int)zw[0] * (t & 63);
  const float* __restrict__ w1v = w1 + lz;
  const float* __restrict__ b1v = b1 + lz;
  const float* __restrict__ w2v = w2 + lz;
  const float* __restrict__ w3v = w3 + wv * 32 + lz;

  float m[32];
#pragma unroll
  for (int o = 0; o < 32; ++o) m[o] = 0.0f;                // relu via max w/ 0

#pragma unroll 1
  for (int tile = 0; tile < 8; ++tile) {
    {
      const int ptg = b * NPTS + half * 512 + tile * 64 + lane;
      const float x0 = data[ptg * 3], x1 = data[ptg * 3 + 1], x2 = data[ptg * 3 + 2];
      float a[8];
#pragma unroll
      for (int c = 0; c < 8; ++c) a[c] = b2[wv * 8 + c];   // s_load (cold, ok)
#pragma unroll 4
      for (int j = 0; j < 64; ++j) {                       // vector loads now
        float hj = fmaf(x0, w1v[j],
                   fmaf(x1, w1v[64 + j],
                   fmaf(x2, w1v[128 + j], b1v[j])));
        hj = fmaxf(hj, 0.0f);
        const float4 wa = *(const float4*)(w2v + j * 128 + wv * 8);
        const float4 wb = *(const float4*)(w2v + j * 128 + wv * 8 + 4);
        a[0] = fmaf(hj, wa.x, a[0]); a[1] = fmaf(hj, wa.y, a[1]);
        a[2] = fmaf(hj, wa.z, a[2]); a[3] = fmaf(hj, wa.w, a[3]);
        a[4] = fmaf(hj, wb.x, a[4]); a[5] = fmaf(hj, wb.y, a[5]);
        a[6] = fmaf(hj, wb.z, a[6]); a[7] = fmaf(hj, wb.w, a[7]);
      }
#pragma unroll
      for (int c = 0; c < 8; ++c) h2t[wv * 8 + c][lane] = fmaxf(a[c], 0.0f);
    }
    __syncthreads();

    float acc[32];
#pragma unroll
    for (int o = 0; o < 32; ++o) acc[o] = b3[wv * 32 + o]; // s_load (cold, ok)
#pragma unroll 4
    for (int k = 0; k < 128; ++k) {
      const float hk = h2t[k][lane];                       // ds_read_b32
      const float* __restrict__ wr = w3v + k * 512;        // vector dwordx4 x8
#pragma unroll
      for (int o4 = 0; o4 < 8; ++o4) {
        const float4 w4 = *(const float4*)(wr + (o4 << 2));
        acc[(o4 << 2) + 0] = fmaf(hk, w4.x, acc[(o4 << 2) + 0]);
        acc[(o4 << 2) + 1] = fmaf(hk, w4.y, acc[(o4 << 2) + 1]);
        acc[(o4 << 2) + 2] = fmaf(hk, w4.z, acc[(o4 << 2) + 2]);
        acc[(o4 << 2) + 3] = fmaf(hk, w4.w, acc[(o4 << 2) + 3]);
      }
    }
#pragma unroll
    for (int o = 0; o < 32; ++o) m[o] = fmaxf(m[o], acc[o]);
    __syncthreads();                                       // h2t reuse guard
  }

#pragma unroll
  for (int off = 32; off > 0; off >>= 1) {
#pragma unroll
    for (int o = 0; o < 32; ++o) m[o] = fmaxf(m[o], __shfl_xor(m[o], off, 64));
  }
  if (lane == 0) {
    unsigned* __restrict__ hr = henc + b * 512 + wv * 32;
#pragma unroll
    for (int o = 0; o < 32; ++o) atomicMax(hr + o, __float_as_uint(m[o]));
  }
}

// ---------------------------------------------------------------------------
// Fast f64 exp (Cody-Waite + degree-13 Taylor, exact 1/k! coeffs, branch-
// free, ~1 ulp for |x| < 700). Perturbs vs libm at ~1e-16 rel -> invisible
// at f32 output rounding (f64-perturbation invariance proven rounds 4-7).
// ---------------------------------------------------------------------------
__device__ __forceinline__ double fexp(double x) {
  const double n = rint(x * 1.44269504088896338700e+00);
  const double r = fma(-n, 1.90821492927058770002e-10,
                       fma(-n, 6.93147180369123816490e-01, x));
  double p = 1.0 / 6227020800.0;                 // 1/13!
  p = fma(p, r, 1.0 / 479001600.0);
  p = fma(p, r, 1.0 / 39916800.0);
  p = fma(p, r, 1.0 / 3628800.0);
  p = fma(p, r, 1.0 / 362880.0);
  p = fma(p, r, 1.0 / 40320.0);
  p = fma(p, r, 1.0 / 5040.0);
  p = fma(p, r, 1.0 / 720.0);
  p = fma(p, r, 1.0 / 120.0);
  p = fma(p, r, 1.0 / 24.0);
  p = fma(p, r, 1.0 / 6.0);
  p = fma(p, r, 0.5);
  p = fma(p, r, 1.0);
  p = fma(p, r, 1.0);
  return ldexp(p, (int)n);
}
__device__ __forceinline__ double fsigm(double x) { return 1.0 / (1.0 + fexp(-x)); }
__device__ __forceinline__ double ftanh(double y) {
  const double e = fexp(-2.0 * y);
  return (1.0 - e) / (1.0 + e);
}

// ---------------------------------------------------------------------------
// GRU rollout, f64 -- ROUND-4 WINNER RESTORED VERBATIM (650us steady).
// grid 256, block 576 (9 waves), 2 barriers/step, plain unroll-2 JIT loads,
// wave-8 concurrent wave-private out_mlp. gru is at its per-CU L2-stream
// roofline (~25 B/cy/CU, invariant to waves/unroll/nt/XCD-demand across
// R5/R7/R8; register-prefetch spills 3x R2/R3/R9). Do not touch.
// ---------------------------------------------------------------------------
__global__ __launch_bounds__(576) void gru_kernel(
    const float* __restrict__ henc,     // [256][512] (maxpool bits)
    const float* __restrict__ mw1, const float* __restrict__ mb1,
    const float* __restrict__ mw2, const float* __restrict__ mb2,
    const float* __restrict__ mw3, const float* __restrict__ mb3,
    const float* __restrict__ wih, const float* __restrict__ wp,
    const float* __restrict__ bih, const float* __restrict__ bhh,
    const float* __restrict__ ow1, const float* __restrict__ ob1,
    const float* __restrict__ ow2, const float* __restrict__ ob2,
    const float* __restrict__ ow3, const float* __restrict__ ob3,
    float* __restrict__ dout) {
  __shared__ __align__(16) double h_l[256];     // single sample
  __shared__ double pp[3][256];                 // half1 partials [gate][c]
  __shared__ __align__(16) float ow1f[16384];   // phase-0 alias: g1(256d)+g2(128d)
  __shared__ __align__(16) float ow2f[4096];
  __shared__ float ow3f[384];
  __shared__ float wihf[4608];
  __shared__ float bihf[768];
  __shared__ double o1_l[64];
  __shared__ double o2_l[64];
  __shared__ double gia_l[6];

  const int t = threadIdx.x;
  const int s = blockIdx.x;                     // sample

  for (int i = t; i < 4608; i += 576) wihf[i] = wih[i];
  for (int i = t; i < 768; i += 576) bihf[i] = bih[i];

  double* const g1_l = (double*)ow1f;           // 256 doubles (phase 0 only)
  double* const g2_l = (double*)ow1f + 256;     // 128 doubles (phase 0 only)

  // ---- phase 0: gru_h init MLP (512->256->128->256), f64 (round-7 math) --
  if (t < 256) {
    const float* __restrict__ hrow = henc + (s << 9);
    double a = (double)mb1[t];
#pragma unroll 4
    for (int k = 0; k < 512; ++k)
      a = fma((double)hrow[k], (double)mw1[k * 256 + t], a);
    g1_l[t] = fmax(a, 0.0);
  }
  __syncthreads();
  if (t < 128) {
    double a = (double)mb2[t];
#pragma unroll 4
    for (int k = 0; k < 256; ++k) a = fma(g1_l[k], (double)mw2[k * 128 + t], a);
    g2_l[t] = fmax(a, 0.0);
  }
  __syncthreads();
  if (t < 256) {
    double a = (double)mb3[t];
#pragma unroll 4
    for (int k = 0; k < 128; ++k) a = fma(g2_l[k], (double)mw3[k * 256 + t], a);
    h_l[t] = a;
  }
  if (t < 6) gia_l[t] = 0.0;
  __syncthreads();                    // phase-0 reads of g1/g2 complete

  // ---- stage out_mlp f32 weights into LDS (overwrites g1/g2 region) ----
  for (int i = t; i < 16384; i += 576) ow1f[i] = ow1[i];
  for (int i = t; i < 4096; i += 576) ow2f[i] = ow2[i];
  if (t < 384) ow3f[t] = ow3[t];
  // (visible to wave 8 after the post-prologue __syncthreads)

  // ---- thread constants ----
  const int c = t & 255;
  const int hh = (t >> 8) & 1;                 // k-half (t<512)
  const int khome = hh << 5;                   // k4 range [khome, khome+32)
  const double br = (t < 512 && hh == 0) ? (double)bhh[c] : 0.0;
  const double bz = (t < 512 && hh == 0) ? (double)bhh[256 + c] : 0.0;
  const double bn = (t < 512 && hh == 0) ? (double)bhh[512 + c] : 0.0;
  double hreg = (t < 256) ? h_l[c] : 0.0;      // own phase-0 write
  const float* const wpc = wp + c * 4;

  // out_mlp constants (wave 8)
  const int ln = t & 63;
  double ob1d = 0.0, ob2d = 0.0, ob3d = 0.0;
  if (t >= 512) {
    ob1d = (double)ob1[ln];
    ob2d = (double)ob2[ln];
    if (ln < 6) ob3d = (double)ob3[ln];
  }

  double ar, az, an;

  // FMA order per k4 identical to round-0's per-sample chain:
  // ar: ha.x,ha.y,hb.x,hb.y then az x4 then an x4, k4 ascending.
#define MV_K(kk) {                                                           \
    const float* p_ = wpc + (khome + (kk)) * 3072;                           \
    const float4 wr = *(const float4*)(p_);                                  \
    const float4 wz = *(const float4*)(p_ + 1024);                           \
    const float4 wn = *(const float4*)(p_ + 2048);                           \
    const double2 ha = *(const double2*)(h_l + ((khome + (kk)) << 2));       \
    const double2 hb = *(const double2*)(h_l + ((khome + (kk)) << 2) + 2);   \
    ar = fma(ha.x, (double)wr.x, ar); ar = fma(ha.y, (double)wr.y, ar);      \
    ar = fma(hb.x, (double)wr.z, ar); ar = fma(hb.y, (double)wr.w, ar);      \
    az = fma(ha.x, (double)wz.x, az); az = fma(ha.y, (double)wz.y, az);      \
    az = fma(hb.x, (double)wz.z, az); az = fma(hb.y, (double)wz.w, az);      \
    an = fma(ha.x, (double)wn.x, an); an = fma(ha.y, (double)wn.y, an);      \
    an = fma(hb.x, (double)wn.z, an); an = fma(hb.y, (double)wn.w, an);      \
  }

  // ---- prologue: both halves' partials of comb(h0) ----
  if (t < 512) {
    ar = br; az = bz; an = bn;
#pragma unroll 2
    for (int kk = 0; kk < 32; ++kk) MV_K(kk)
    if (hh) { pp[0][c] = ar; pp[1][c] = az; pp[2][c] = an; }
  }
  __syncthreads();                    // pp + staged LDS weights visible

#pragma unroll 1
  for (int step = 0; step < T_; ++step) {
    // ---- gates (t<256): comb = own half0 (biased) + half1 from pp ----
    if (t < 256) {
      const double cr = ar + pp[0][c];
      const double cz = az + pp[1][c];
      const double cn = an + pp[2][c];
      double gr = (double)bihf[c], gz = (double)bihf[256 + c],
             gn = (double)bihf[512 + c];
#pragma unroll
      for (int a = 0; a < 6; ++a) {
        const double xa = gia_l[a];
        gr = fma((double)wihf[c * 6 + a], xa, gr);
        gz = fma((double)wihf[(256 + c) * 6 + a], xa, gz);
        gn = fma((double)wihf[(512 + c) * 6 + a], xa, gn);
      }
      const double rv = fsigm(cr + gr);
      const double zv = fsigm(cz + gz);
      const double nv = ftanh(fma(rv, cn, gn));
      hreg = fma(zv, hreg - nv, nv);
      h_l[c] = hreg;
    }
    if (t < 512) { ar = br; az = bz; an = bn; }
    __syncthreads();                  // [A] h published

    if (t < 512) {
      // ---- matvec: one plain 32-k4 pass (compiler-scheduled loads) ----
#pragma unroll 2
      for (int kk = 0; kk < 32; ++kk) MV_K(kk)
      if (hh) { pp[0][c] = ar; pp[1][c] = az; pp[2][c] = an; }
    } else {
      // ---- out_mlp, wave-private (wave 8) ----
      double a0 = ob1d, a1 = 0.0;     // (ob1 + asc lo) + (asc hi): proven assoc
#pragma unroll 4
      for (int k = 0; k < 128; ++k) {
        a0 = fma(h_l[k], (double)ow1f[k * 64 + ln], a0);
        a1 = fma(h_l[128 + k], (double)ow1f[(128 + k) * 64 + ln], a1);
      }
      o1_l[ln] = fmax(a0 + a1, 0.0);
      __builtin_amdgcn_wave_barrier();                    // own-wave LDS only
      double b0 = ob2d;
#pragma unroll 4
      for (int k = 0; k < 64; ++k)
        b0 = fma(o1_l[k], (double)ow2f[k * 64 + ln], b0);
      o2_l[ln] = fmax(b0, 0.0);
      __builtin_amdgcn_wave_barrier();
      if (ln < 6) {
        double a = ob3d;
#pragma unroll 4
        for (int k = 0; k < 64; ++k)
          a = fma(o2_l[k], (double)ow3f[k * 6 + ln], a);
        const double gi_new = gia_l[ln] + a;
        gia_l[ln] = gi_new;
        dout[s * 300 + step * 6 + ln] = (float)a;              // dws
        dout[76800 + s * 300 + step * 6 + ln] = (float)gi_new; // ws
      }
    }
    __syncthreads();                  // [B] pp + gia ready for next gates
  }
#undef MV_K
}

extern "C" void kernel_launch(void* const* d_in, const int* in_sizes, int n_in,
                              void* d_out, int out_size, void* d_ws, size_t ws_size,
                              hipStream_t stream) {
  const float* data = (const float*)d_in[0];
  // d_in[1] = horizon (always 50)
  const float* ew1 = (const float*)d_in[2];
  const float* eb1 = (const float*)d_in[3];
  const float* ew2 = (const float*)d_in[4];
  const float* eb2 = (const float*)d_in[5];
  const float* ew3 = (const float*)d_in[6];
  const float* eb3 = (const float*)d_in[7];
  const float* mw1 = (const float*)d_in[8];
  const float* mb1 = (const float*)d_in[9];
  const float* mw2 = (const float*)d_in[10];
  const float* mb2 = (const float*)d_in[11];
  const float* mw3 = (const float*)d_in[12];
  const float* mb3 = (const float*)d_in[13];
  const float* wih = (const float*)d_in[14];
  const float* whh = (const float*)d_in[15];
  const float* bih = (const float*)d_in[16];
  const float* bhh = (const float*)d_in[17];
  const float* ow1 = (const float*)d_in[18];
  const float* ob1 = (const float*)d_in[19];
  const float* ow2 = (const float*)d_in[20];
  const float* ob2 = (const float*)d_in[21];
  const float* ow3 = (const float*)d_in[22];
  const float* ob3 = (const float*)d_in[23];
  float* out = (float*)d_out;

  char* ws = (char*)d_ws;
  float*    wp   = (float*)(ws);                 // 786432 B
  unsigned* henc = (unsigned*)(ws + 786432);     // 524288 B
  unsigned* zw   = (unsigned*)(ws + 1310720);    // 4 B runtime zero

  prep_kernel<<<768, 256, 0, stream>>>(whh, wp, henc, zw);
  enc_kernel<<<512, 1024, 0, stream>>>(data, ew1, eb1, ew2, eb2, ew3, eb3,
                                       henc, zw);
  gru_kernel<<<256, 576, 0, stream>>>((const float*)henc,
                                      mw1, mb1, mw2, mb2, mw3, mb3,
                                      wih, wp, bih, bhh,
                                      ow1, ob1, ow2, ob2, ow3, ob3,
                                      out);
}

// Round 11
// 1132.042 us; speedup vs baseline: 2.7691x; 2.5023x over previous
//
#include <hip/hip_runtime.h>
#include <math.h>

// Problem constants
#define B_    256
#define NPTS  1024
#define T_    50

// ---------------------------------------------------------------------------
// ws layout (bytes):
//   [0,       786432)   wp   f32 [64][3][256][4]  packed W_hh (round-7 layout)
//   [786432,  1310720)  henc u32 [256][512]       (f32-bit maxpool via atomicMax)
// ---------------------------------------------------------------------------

__global__ __launch_bounds__(256) void prep_kernel(
    const float* __restrict__ whh, float* __restrict__ wp,
    unsigned* __restrict__ henc) {
  int idx = blockIdx.x * 256 + threadIdx.x;   // grid 768*256 = 196608
  if (idx < 196608) {
    int c = idx & 3;
    int r = idx >> 2;            // (k4*3+j)*256 + t
    int t2 = r & 255;
    int q = r >> 8;              // k4*3 + j
    int j = q % 3;
    int k4 = q / 3;
    wp[idx] = whh[(j * 256 + t2) * 256 + (k4 * 4 + c)];
  }
  if (idx < 131072) henc[idx] = 0u;           // bits 0 == +0.0f; relu>=0 valid
}

// ---------------------------------------------------------------------------
// Encoder. Round-19 delta vs the passing R4 version: TWO TILES PER PASS.
// R10 post-mortem: vector-path broadcast loads are 4.7x WORSE -- wave-
// uniform weights belong on the scalar path. The real cost is sK$ miss
// FREQUENCY: each wave re-streams its 16KB w3 slice 8x (once/tile), and
// 16 waves x 16KB disjoint slices thrash the 16KB sK$ -> all misses.
// Fix: h2t[2][...] holds two tiles (67.6KB LDS; gru already uses 112KB
// static so >64KB is proven fine); the L3 k-loop reads ONE w3 row per k
// and feeds TWO acc chains -> per-tile scalar traffic and lgkmcnt stall
// exposure halve (8 -> 4 w3 passes/block).
// Numerics: each acc chain keeps R4's exact b3 seed + ascending-k FMA
// order; phase-1 body is R4 verbatim per tile; m-update is pure fmax in
// tile order (exact). Output bit-identical.
// ---------------------------------------------------------------------------
__global__ __launch_bounds__(1024) void enc_kernel(
    const float* __restrict__ data,
    const float* __restrict__ w1, const float* __restrict__ b1,
    const float* __restrict__ w2, const float* __restrict__ b2,
    const float* __restrict__ w3, const float* __restrict__ b3,
    unsigned* __restrict__ henc) {
  __shared__ float h2t[2][128][66];
  const int t = threadIdx.x;
  const int b = blockIdx.x >> 1;
  const int half = blockIdx.x & 1;
  const int lane = t & 63;
  const int wv = __builtin_amdgcn_readfirstlane(t >> 6);   // wave id 0..15

  float m[32];
#pragma unroll
  for (int o = 0; o < 32; ++o) m[o] = 0.0f;                // relu via max w/ 0
  const float* __restrict__ w3b = w3 + wv * 32;

#pragma unroll 1
  for (int pair = 0; pair < 4; ++pair) {
#pragma unroll
    for (int tt = 0; tt < 2; ++tt) {                       // R4 phase-1 x2
      const int ptg = b * NPTS + half * 512 + (pair * 2 + tt) * 64 + lane;
      const float x0 = data[ptg * 3], x1 = data[ptg * 3 + 1], x2 = data[ptg * 3 + 2];
      float a[8];
#pragma unroll
      for (int c = 0; c < 8; ++c) a[c] = b2[wv * 8 + c];   // s_load
#pragma unroll 4
      for (int j = 0; j < 64; ++j) {                       // w1/b1 uniform
        float hj = fmaf(x0, w1[j], fmaf(x1, w1[64 + j], fmaf(x2, w1[128 + j], b1[j])));
        hj = fmaxf(hj, 0.0f);
        const float* __restrict__ w2r = w2 + j * 128 + wv * 8;  // s_load x8
#pragma unroll
        for (int c = 0; c < 8; ++c) a[c] = fmaf(hj, w2r[c], a[c]);
      }
#pragma unroll
      for (int c = 0; c < 8; ++c) h2t[tt][wv * 8 + c][lane] = fmaxf(a[c], 0.0f);
    }
    __syncthreads();

    float acc0[32], acc1[32];
#pragma unroll
    for (int o = 0; o < 32; ++o) {
      acc0[o] = b3[wv * 32 + o];                           // s_load seed (R4)
      acc1[o] = acc0[o];                                   // same b3 value
    }
#pragma unroll 4
    for (int k = 0; k < 128; ++k) {
      const float hk0 = h2t[0][k][lane];                   // ds_read_b32
      const float hk1 = h2t[1][k][lane];                   // ds_read_b32
      const float* __restrict__ wr = w3b + k * 512;        // ONE s_load row
#pragma unroll
      for (int o = 0; o < 32; ++o) {
        const float w = wr[o];
        acc0[o] = fmaf(hk0, w, acc0[o]);
        acc1[o] = fmaf(hk1, w, acc1[o]);
      }
    }
#pragma unroll
    for (int o = 0; o < 32; ++o)
      m[o] = fmaxf(fmaxf(m[o], acc0[o]), acc1[o]);         // tile order, exact
    __syncthreads();                                       // h2t reuse guard
  }

#pragma unroll
  for (int off = 32; off > 0; off >>= 1) {
#pragma unroll
    for (int o = 0; o < 32; ++o) m[o] = fmaxf(m[o], __shfl_xor(m[o], off, 64));
  }
  if (lane == 0) {
    unsigned* __restrict__ hr = henc + b * 512 + wv * 32;
#pragma unroll
    for (int o = 0; o < 32; ++o) atomicMax(hr + o, __float_as_uint(m[o]));
  }
}

// ---------------------------------------------------------------------------
// Fast f64 exp (Cody-Waite + degree-13 Taylor, exact 1/k! coeffs, branch-
// free, ~1 ulp for |x| < 700). Perturbs vs libm at ~1e-16 rel -> invisible
// at f32 output rounding (f64-perturbation invariance proven rounds 4-7).
// ---------------------------------------------------------------------------
__device__ __forceinline__ double fexp(double x) {
  const double n = rint(x * 1.44269504088896338700e+00);
  const double r = fma(-n, 1.90821492927058770002e-10,
                       fma(-n, 6.93147180369123816490e-01, x));
  double p = 1.0 / 6227020800.0;                 // 1/13!
  p = fma(p, r, 1.0 / 479001600.0);
  p = fma(p, r, 1.0 / 39916800.0);
  p = fma(p, r, 1.0 / 3628800.0);
  p = fma(p, r, 1.0 / 362880.0);
  p = fma(p, r, 1.0 / 40320.0);
  p = fma(p, r, 1.0 / 5040.0);
  p = fma(p, r, 1.0 / 720.0);
  p = fma(p, r, 1.0 / 120.0);
  p = fma(p, r, 1.0 / 24.0);
  p = fma(p, r, 1.0 / 6.0);
  p = fma(p, r, 0.5);
  p = fma(p, r, 1.0);
  p = fma(p, r, 1.0);
  return ldexp(p, (int)n);
}
__device__ __forceinline__ double fsigm(double x) { return 1.0 / (1.0 + fexp(-x)); }
__device__ __forceinline__ double ftanh(double y) {
  const double e = fexp(-2.0 * y);
  return (1.0 - e) / (1.0 + e);
}

// ---------------------------------------------------------------------------
// GRU rollout, f64 -- ROUND-4 WINNER VERBATIM (650us steady).
// grid 256, block 576 (9 waves), 2 barriers/step, plain unroll-2 JIT loads,
// wave-8 concurrent wave-private out_mlp. gru is at its per-CU L2-stream
// roofline (~25 B/cy/CU, invariant to waves/unroll/nt/XCD-demand across
// R5/R7/R8; register-prefetch spills 3x R2/R3/R9). Do not touch.
// ---------------------------------------------------------------------------
__global__ __launch_bounds__(576) void gru_kernel(
    const float* __restrict__ henc,     // [256][512] (maxpool bits)
    const float* __restrict__ mw1, const float* __restrict__ mb1,
    const float* __restrict__ mw2, const float* __restrict__ mb2,
    const float* __restrict__ mw3, const float* __restrict__ mb3,
    const float* __restrict__ wih, const float* __restrict__ wp,
    const float* __restrict__ bih, const float* __restrict__ bhh,
    const float* __restrict__ ow1, const float* __restrict__ ob1,
    const float* __restrict__ ow2, const float* __restrict__ ob2,
    const float* __restrict__ ow3, const float* __restrict__ ob3,
    float* __restrict__ dout) {
  __shared__ __align__(16) double h_l[256];     // single sample
  __shared__ double pp[3][256];                 // half1 partials [gate][c]
  __shared__ __align__(16) float ow1f[16384];   // phase-0 alias: g1(256d)+g2(128d)
  __shared__ __align__(16) float ow2f[4096];
  __shared__ float ow3f[384];
  __shared__ float wihf[4608];
  __shared__ float bihf[768];
  __shared__ double o1_l[64];
  __shared__ double o2_l[64];
  __shared__ double gia_l[6];

  const int t = threadIdx.x;
  const int s = blockIdx.x;                     // sample

  for (int i = t; i < 4608; i += 576) wihf[i] = wih[i];
  for (int i = t; i < 768; i += 576) bihf[i] = bih[i];

  double* const g1_l = (double*)ow1f;           // 256 doubles (phase 0 only)
  double* const g2_l = (double*)ow1f + 256;     // 128 doubles (phase 0 only)

  // ---- phase 0: gru_h init MLP (512->256->128->256), f64 (round-7 math) --
  if (t < 256) {
    const float* __restrict__ hrow = henc + (s << 9);
    double a = (double)mb1[t];
#pragma unroll 4
    for (int k = 0; k < 512; ++k)
      a = fma((double)hrow[k], (double)mw1[k * 256 + t], a);
    g1_l[t] = fmax(a, 0.0);
  }
  __syncthreads();
  if (t < 128) {
    double a = (double)mb2[t];
#pragma unroll 4
    for (int k = 0; k < 256; ++k) a = fma(g1_l[k], (double)mw2[k * 128 + t], a);
    g2_l[t] = fmax(a, 0.0);
  }
  __syncthreads();
  if (t < 256) {
    double a = (double)mb3[t];
#pragma unroll 4
    for (int k = 0; k < 128; ++k) a = fma(g2_l[k], (double)mw3[k * 256 + t], a);
    h_l[t] = a;
  }
  if (t < 6) gia_l[t] = 0.0;
  __syncthreads();                    // phase-0 reads of g1/g2 complete

  // ---- stage out_mlp f32 weights into LDS (overwrites g1/g2 region) ----
  for (int i = t; i < 16384; i += 576) ow1f[i] = ow1[i];
  for (int i = t; i < 4096; i += 576) ow2f[i] = ow2[i];
  if (t < 384) ow3f[t] = ow3[t];
  // (visible to wave 8 after the post-prologue __syncthreads)

  // ---- thread constants ----
  const int c = t & 255;
  const int hh = (t >> 8) & 1;                 // k-half (t<512)
  const int khome = hh << 5;                   // k4 range [khome, khome+32)
  const double br = (t < 512 && hh == 0) ? (double)bhh[c] : 0.0;
  const double bz = (t < 512 && hh == 0) ? (double)bhh[256 + c] : 0.0;
  const double bn = (t < 512 && hh == 0) ? (double)bhh[512 + c] : 0.0;
  double hreg = (t < 256) ? h_l[c] : 0.0;      // own phase-0 write
  const float* const wpc = wp + c * 4;

  // out_mlp constants (wave 8)
  const int ln = t & 63;
  double ob1d = 0.0, ob2d = 0.0, ob3d = 0.0;
  if (t >= 512) {
    ob1d = (double)ob1[ln];
    ob2d = (double)ob2[ln];
    if (ln < 6) ob3d = (double)ob3[ln];
  }

  double ar, az, an;

  // FMA order per k4 identical to round-0's per-sample chain:
  // ar: ha.x,ha.y,hb.x,hb.y then az x4 then an x4, k4 ascending.
#define MV_K(kk) {                                                           \
    const float* p_ = wpc + (khome + (kk)) * 3072;                           \
    const float4 wr = *(const float4*)(p_);                                  \
    const float4 wz = *(const float4*)(p_ + 1024);                           \
    const float4 wn = *(const float4*)(p_ + 2048);                           \
    const double2 ha = *(const double2*)(h_l + ((khome + (kk)) << 2));       \
    const double2 hb = *(const double2*)(h_l + ((khome + (kk)) << 2) + 2);   \
    ar = fma(ha.x, (double)wr.x, ar); ar = fma(ha.y, (double)wr.y, ar);      \
    ar = fma(hb.x, (double)wr.z, ar); ar = fma(hb.y, (double)wr.w, ar);      \
    az = fma(ha.x, (double)wz.x, az); az = fma(ha.y, (double)wz.y, az);      \
    az = fma(hb.x, (double)wz.z, az); az = fma(hb.y, (double)wz.w, az);      \
    an = fma(ha.x, (double)wn.x, an); an = fma(ha.y, (double)wn.y, an);      \
    an = fma(hb.x, (double)wn.z, an); an = fma(hb.y, (double)wn.w, an);      \
  }

  // ---- prologue: both halves' partials of comb(h0) ----
  if (t < 512) {
    ar = br; az = bz; an = bn;
#pragma unroll 2
    for (int kk = 0; kk < 32; ++kk) MV_K(kk)
    if (hh) { pp[0][c] = ar; pp[1][c] = az; pp[2][c] = an; }
  }
  __syncthreads();                    // pp + staged LDS weights visible

#pragma unroll 1
  for (int step = 0; step < T_; ++step) {
    // ---- gates (t<256): comb = own half0 (biased) + half1 from pp ----
    if (t < 256) {
      const double cr = ar + pp[0][c];
      const double cz = az + pp[1][c];
      const double cn = an + pp[2][c];
      double gr = (double)bihf[c], gz = (double)bihf[256 + c],
             gn = (double)bihf[512 + c];
#pragma unroll
      for (int a = 0; a < 6; ++a) {
        const double xa = gia_l[a];
        gr = fma((double)wihf[c * 6 + a], xa, gr);
        gz = fma((double)wihf[(256 + c) * 6 + a], xa, gz);
        gn = fma((double)wihf[(512 + c) * 6 + a], xa, gn);
      }
      const double rv = fsigm(cr + gr);
      const double zv = fsigm(cz + gz);
      const double nv = ftanh(fma(rv, cn, gn));
      hreg = fma(zv, hreg - nv, nv);
      h_l[c] = hreg;
    }
    if (t < 512) { ar = br; az = bz; an = bn; }
    __syncthreads();                  // [A] h published

    if (t < 512) {
      // ---- matvec: one plain 32-k4 pass (compiler-scheduled loads) ----
#pragma unroll 2
      for (int kk = 0; kk < 32; ++kk) MV_K(kk)
      if (hh) { pp[0][c] = ar; pp[1][c] = az; pp[2][c] = an; }
    } else {
      // ---- out_mlp, wave-private (wave 8) ----
      double a0 = ob1d, a1 = 0.0;     // (ob1 + asc lo) + (asc hi): proven assoc
#pragma unroll 4
      for (int k = 0; k < 128; ++k) {
        a0 = fma(h_l[k], (double)ow1f[k * 64 + ln], a0);
        a1 = fma(h_l[128 + k], (double)ow1f[(128 + k) * 64 + ln], a1);
      }
      o1_l[ln] = fmax(a0 + a1, 0.0);
      __builtin_amdgcn_wave_barrier();                    // own-wave LDS only
      double b0 = ob2d;
#pragma unroll 4
      for (int k = 0; k < 64; ++k)
        b0 = fma(o1_l[k], (double)ow2f[k * 64 + ln], b0);
      o2_l[ln] = fmax(b0, 0.0);
      __builtin_amdgcn_wave_barrier();
      if (ln < 6) {
        double a = ob3d;
#pragma unroll 4
        for (int k = 0; k < 64; ++k)
          a = fma(o2_l[k], (double)ow3f[k * 6 + ln], a);
        const double gi_new = gia_l[ln] + a;
        gia_l[ln] = gi_new;
        dout[s * 300 + step * 6 + ln] = (float)a;              // dws
        dout[76800 + s * 300 + step * 6 + ln] = (float)gi_new; // ws
      }
    }
    __syncthreads();                  // [B] pp + gia ready for next gates
  }
#undef MV_K
}

extern "C" void kernel_launch(void* const* d_in, const int* in_sizes, int n_in,
                              void* d_out, int out_size, void* d_ws, size_t ws_size,
                              hipStream_t stream) {
  const float* data = (const float*)d_in[0];
  // d_in[1] = horizon (always 50)
  const float* ew1 = (const float*)d_in[2];
  const float* eb1 = (const float*)d_in[3];
  const float* ew2 = (const float*)d_in[4];
  const float* eb2 = (const float*)d_in[5];
  const float* ew3 = (const float*)d_in[6];
  const float* eb3 = (const float*)d_in[7];
  const float* mw1 = (const float*)d_in[8];
  const float* mb1 = (const float*)d_in[9];
  const float* mw2 = (const float*)d_in[10];
  const float* mb2 = (const float*)d_in[11];
  const float* mw3 = (const float*)d_in[12];
  const float* mb3 = (const float*)d_in[13];
  const float* wih = (const float*)d_in[14];
  const float* whh = (const float*)d_in[15];
  const float* bih = (const float*)d_in[16];
  const float* bhh = (const float*)d_in[17];
  const float* ow1 = (const float*)d_in[18];
  const float* ob1 = (const float*)d_in[19];
  const float* ow2 = (const float*)d_in[20];
  const float* ob2 = (const float*)d_in[21];
  const float* ow3 = (const float*)d_in[22];
  const float* ob3 = (const float*)d_in[23];
  float* out = (float*)d_out;

  char* ws = (char*)d_ws;
  float*    wp   = (float*)(ws);                 // 786432 B
  unsigned* henc = (unsigned*)(ws + 786432);     // 524288 B -> end 1310720

  prep_kernel<<<768, 256, 0, stream>>>(whh, wp, henc);
  enc_kernel<<<512, 1024, 0, stream>>>(data, ew1, eb1, ew2, eb2, ew3, eb3, henc);
  gru_kernel<<<256, 576, 0, stream>>>((const float*)henc,
                                      mw1, mb1, mw2, mb2, mw3, mb3,
                                      wih, wp, bih, bhh,
                                      ow1, ob1, ow2, ob2, ow3, ob3,
                                      out);
}